// Round 1
// baseline (745.370 us; speedup 1.0000x reference)
//
#include <hip/hip_runtime.h>

// Flat dot-product reduction: out = (1/N) * sum_i probs[i]*centroids[i].
// Memory-bound: 808 MB read @ ~6.3 TB/s -> ~128 us floor.

__global__ void dot_reduce_kernel(const float4* __restrict__ p4,
                                  const float4* __restrict__ c4,
                                  const float* __restrict__ p,
                                  const float* __restrict__ c,
                                  long n4, long total, double* __restrict__ ws) {
    float acc = 0.0f;
    long tid = (long)blockIdx.x * blockDim.x + threadIdx.x;
    long stride = (long)gridDim.x * blockDim.x;
    for (long i = tid; i < n4; i += stride) {
        float4 a = p4[i];
        float4 b = c4[i];
        acc += a.x * b.x + a.y * b.y + a.z * b.z + a.w * b.w;
    }
    // scalar tail (total % 4), handled by first threads
    long tail_start = n4 * 4;
    for (long i = tail_start + tid; i < total; i += stride) {
        acc += p[i] * c[i];
    }

    // wave-64 shuffle reduction
    #pragma unroll
    for (int off = 32; off > 0; off >>= 1)
        acc += __shfl_down(acc, off, 64);

    __shared__ float wave_sums[4];  // 256 threads / 64 lanes = 4 waves
    int lane = threadIdx.x & 63;
    int wid  = threadIdx.x >> 6;
    if (lane == 0) wave_sums[wid] = acc;
    __syncthreads();
    if (threadIdx.x == 0) {
        float s = wave_sums[0] + wave_sums[1] + wave_sums[2] + wave_sums[3];
        atomicAdd(ws, (double)s);  // device-scope by default (G12)
    }
}

__global__ void finalize_kernel(const double* __restrict__ ws,
                                float* __restrict__ out, double inv_n) {
    out[0] = (float)(ws[0] * inv_n);
}

extern "C" void kernel_launch(void* const* d_in, const int* in_sizes, int n_in,
                              void* d_out, int out_size, void* d_ws, size_t ws_size,
                              hipStream_t stream) {
    const float* probs     = (const float*)d_in[0];
    const float* centroids = (const float*)d_in[1];
    float* out = (float*)d_out;
    double* ws = (double*)d_ws;

    long total = (long)in_sizes[0];      // N*K = 101,000,000
    long n4    = total / 4;
    long rows  = total / 101;            // K = 101 per the reference

    // d_ws is re-poisoned to 0xAA before every call — zero the accumulator.
    hipMemsetAsync(ws, 0, sizeof(double), stream);

    dim3 block(256);
    dim3 grid(2048);
    dot_reduce_kernel<<<grid, block, 0, stream>>>(
        (const float4*)probs, (const float4*)centroids,
        probs, centroids, n4, total, ws);

    finalize_kernel<<<1, 1, 0, stream>>>(ws, out, 1.0 / (double)rows);
}

// Round 2
// 738.077 us; speedup vs baseline: 1.0099x; 1.0099x over previous
//
#include <hip/hip_runtime.h>

// Flat dot-product reduction: out = (1/N) * sum_i probs[i]*centroids[i].
// Memory-bound: 808 MB read @ ~6.3 TB/s -> ~128 us floor.
// R2: removed contended fp64 atomic (2048 blocks -> same address was a
// serialized ~100us tail). Blocks store partials to ws[]; finalize kernel
// reduces them. 4 independent FMA chains via float4 accumulator.

#define NBLOCKS 2048
#define NTHREADS 256

__global__ void dot_reduce_kernel(const float4* __restrict__ p4,
                                  const float4* __restrict__ c4,
                                  long n4, float* __restrict__ partials) {
    float4 acc = {0.f, 0.f, 0.f, 0.f};
    long tid = (long)blockIdx.x * blockDim.x + threadIdx.x;
    long stride = (long)gridDim.x * blockDim.x;
    for (long i = tid; i < n4; i += stride) {
        float4 a = p4[i];
        float4 b = c4[i];
        acc.x += a.x * b.x;
        acc.y += a.y * b.y;
        acc.z += a.z * b.z;
        acc.w += a.w * b.w;
    }
    float s = (acc.x + acc.y) + (acc.z + acc.w);

    // wave-64 shuffle reduction
    #pragma unroll
    for (int off = 32; off > 0; off >>= 1)
        s += __shfl_down(s, off, 64);

    __shared__ float wave_sums[NTHREADS / 64];
    int lane = threadIdx.x & 63;
    int wid  = threadIdx.x >> 6;
    if (lane == 0) wave_sums[wid] = s;
    __syncthreads();
    if (threadIdx.x == 0) {
        partials[blockIdx.x] = (wave_sums[0] + wave_sums[1]) +
                               (wave_sums[2] + wave_sums[3]);
    }
}

__global__ void finalize_kernel(const float* __restrict__ partials,
                                float* __restrict__ out, double inv_n) {
    // one block, 256 threads; each sums NBLOCKS/256 = 8 partials in double
    double s = 0.0;
    for (int i = threadIdx.x; i < NBLOCKS; i += NTHREADS)
        s += (double)partials[i];

    #pragma unroll
    for (int off = 32; off > 0; off >>= 1)
        s += __shfl_down(s, off, 64);

    __shared__ double wave_sums[NTHREADS / 64];
    int lane = threadIdx.x & 63;
    int wid  = threadIdx.x >> 6;
    if (lane == 0) wave_sums[wid] = s;
    __syncthreads();
    if (threadIdx.x == 0) {
        double tot = (wave_sums[0] + wave_sums[1]) +
                     (wave_sums[2] + wave_sums[3]);
        out[0] = (float)(tot * inv_n);
    }
}

extern "C" void kernel_launch(void* const* d_in, const int* in_sizes, int n_in,
                              void* d_out, int out_size, void* d_ws, size_t ws_size,
                              hipStream_t stream) {
    const float* probs     = (const float*)d_in[0];
    const float* centroids = (const float*)d_in[1];
    float* out = (float*)d_out;
    float* partials = (float*)d_ws;   // NBLOCKS floats of scratch

    long total = (long)in_sizes[0];   // N*K = 101,000,000 (divisible by 4)
    long n4    = total / 4;
    long rows  = total / 101;         // K = 101 per the reference

    dot_reduce_kernel<<<dim3(NBLOCKS), dim3(NTHREADS), 0, stream>>>(
        (const float4*)probs, (const float4*)centroids, n4, partials);

    finalize_kernel<<<1, NTHREADS, 0, stream>>>(partials, out, 1.0 / (double)rows);
}